// Round 9
// baseline (98.160 us; speedup 1.0000x reference)
//
#include <hip/hip_runtime.h>

// OriEmbeddingBlock: TensorProduct(1o x 1o -> 128x0e + 128x1e + 128x2e), uvw, shared weights.
//  - l=1 output block (cols 128..511, chunks 32..127) is identically ZERO.
//  - e3nn l=1 basis order within an ori row: 0=y, 1=z, 2=x.
//  - cols 0..127:   w0[col] * |v|^2 / sqrt(3)
//  - cols 512..1151: j=col-512, w2[j/5] * s2[j%5],
//    s2 = [sqrt(2)xy, sqrt(2)yz, sqrt(1/6)(2z^2-x^2-y^2), sqrt(2)zx, sqrt(1/2)(x^2-y^2)]
// v8: SPLIT DISPATCH. Zero block (153.6 MB) written by a literal fill-clone kernel
//     (pure stores, no loads/math — the thing that demonstrably runs at 6.9 TB/s);
//     nonzero cols (307.2 MB) by the v5-style compute kernel (plateaus at 4.9).
//     Decisive test: if the fill-clone portion runs at fill rate, limiter is
//     compute-store interleave; if both plateau, we're at the dispatch-size wall.

typedef float v4f __attribute__((ext_vector_type(4)));

// ---------------- Kernel A: zero-fill clone (chunks 32..127 of each row) -------
#define ZT 256
#define ZGRID 513            // *256 = 131328 threads = 1368 row-groups of 96

__global__ __launch_bounds__(ZT) void zero_fill_kernel(float* __restrict__ out,
                                                       int n_rows)
{
    v4f* __restrict__ out4 = reinterpret_cast<v4f*>(out);
    const int tid = blockIdx.x * ZT + threadIdx.x;
    const int cic = tid % 96;                 // chunk-in-zone, loop-invariant
    int row = tid / 96;
    const int rstride = (ZGRID * ZT) / 96;    // 1368
    v4f z = {0.0f, 0.0f, 0.0f, 0.0f};
    for (; row < n_rows; row += rstride)
        out4[(size_t)row * 288 + 32 + cic] = z;   // pure store stream, fill-style
}

// ---------------- Kernel B: compute nonzero cols (chunks 0..31, 128..287) ------
#define BT 256
#define BCPR 96              // threads per row; each owns zone-chunks c and c+96
#define BGRID 939            // multiple of 3 -> 939*256/96 = 2504 groups
#define BRPG 40              // rows per group; 2500*40 = 100000 exactly
#define BBATCH 8
#define BNB 5

__device__ __forceinline__ void emit_row(v4f* __restrict__ out4, int n,
                                         int g1, int g2,
                                         float vy, float vz, float vx,
                                         const float coef[8], const int sel[8]) {
    const float xx = vx * vx, yy = vy * vy, zz = vz * vz;
    const float s0 = (xx + yy + zz) * 0.57735026918962576f;
    const float s1 = 1.41421356237309505f * (vx * vy);
    const float s2 = 1.41421356237309505f * (vy * vz);
    const float s3 = 0.40824829046386302f * (2.0f * zz - xx - yy);
    const float s4 = 1.41421356237309505f * (vz * vx);
    const float s5 = 0.70710678118654752f * (xx - yy);
    float r[8];
#pragma unroll
    for (int i = 0; i < 8; ++i) {
        float t = s0;
        t = (sel[i] == 1) ? s1 : t;
        t = (sel[i] == 2) ? s2 : t;
        t = (sel[i] == 3) ? s3 : t;
        t = (sel[i] == 4) ? s4 : t;
        t = (sel[i] == 5) ? s5 : t;
        r[i] = coef[i] * t;
    }
    const size_t rb = (size_t)n * 288;
    v4f a = {r[0], r[1], r[2], r[3]};
    v4f b = {r[4], r[5], r[6], r[7]};
    out4[rb + g1] = a;
    out4[rb + g2] = b;
}

__global__ __launch_bounds__(BT, 4) void compute_kernel(
    const float* __restrict__ ori,
    const float* __restrict__ weights,
    float* __restrict__ out,
    int n_rows)
{
    const int tid = blockIdx.x * BT + threadIdx.x;
    const int c = tid % BCPR;           // owns zone-chunks z = c and c+96
    const int g = tid / BCPR;
    const int r0 = g * BRPG;
    if (r0 >= n_rows) return;

    // zone-chunk z -> col(z) = z<32 ? 4z : 4z+384 ; global chunk = z<32 ? z : z+96
    float coef[8];
    int sel[8];
    int gch[2];
#pragma unroll
    for (int h = 0; h < 2; ++h) {
        const int z = c + 96 * h;
        const int col0 = (z < 32) ? 4 * z : 4 * z + 384;
        gch[h] = (z < 32) ? z : z + 96;
#pragma unroll
        for (int k = 0; k < 4; ++k) {
            const int col = col0 + k;
            if (col < 128) { coef[4 * h + k] = weights[col];  sel[4 * h + k] = 0; }
            else { const int j = col - 512;
                   coef[4 * h + k] = weights[256 + j / 5];    sel[4 * h + k] = 1 + j % 5; }
        }
    }

    v4f* __restrict__ out4 = reinterpret_cast<v4f*>(out);
    const v4f* __restrict__ src = reinterpret_cast<const v4f*>(ori);

    const int nb = min(BNB, (n_rows - r0) / BBATCH);   // N=100000 -> always 5
    const int base = 30 * g;                           // 3*r0/4 (aligned: r0 % 4 == 0)

    v4f cur[6], nxt[6];
    if (nb > 0) {
#pragma unroll
        for (int k = 0; k < 6; ++k) cur[k] = src[base + k];
    }
    for (int b = 0; b < nb; ++b) {
        const bool more = (b + 1 < nb);
        if (more) {
#pragma unroll
            for (int k = 0; k < 6; ++k) nxt[k] = src[base + 6 * (b + 1) + k];
        }
        const float* f = reinterpret_cast<const float*>(cur);
        const int rb = r0 + b * BBATCH;
#pragma unroll
        for (int j = 0; j < BBATCH; ++j)
            emit_row(out4, rb + j, gch[0], gch[1],
                     f[3 * j + 0], f[3 * j + 1], f[3 * j + 2], coef, sel);
        if (more) {
#pragma unroll
            for (int k = 0; k < 6; ++k) cur[k] = nxt[k];
        }
    }

    // generic guarded tail (unused at N=100000)
    const int rend = min(r0 + BRPG, n_rows);
    for (int n = r0 + nb * BBATCH; n < rend; ++n)
        emit_row(out4, n, gch[0], gch[1],
                 ori[3 * n + 0], ori[3 * n + 1], ori[3 * n + 2], coef, sel);
}

extern "C" void kernel_launch(void* const* d_in, const int* in_sizes, int n_in,
                              void* d_out, int out_size, void* d_ws, size_t ws_size,
                              hipStream_t stream) {
    const float* ori = (const float*)d_in[0];
    const float* weights = (const float*)d_in[1];
    float* out = (float*)d_out;
    const int n_rows = in_sizes[0] / 3;

    hipLaunchKernelGGL(zero_fill_kernel, dim3(ZGRID), dim3(ZT), 0, stream,
                       out, n_rows);
    hipLaunchKernelGGL(compute_kernel, dim3(BGRID), dim3(BT), 0, stream,
                       ori, weights, out, n_rows);
}

// Round 10
// 93.201 us; speedup vs baseline: 1.0532x; 1.0532x over previous
//
#include <hip/hip_runtime.h>

// OriEmbeddingBlock: TensorProduct(1o x 1o -> 128x0e + 128x1e + 128x2e), uvw, shared weights.
//  - l=1 output block (cols 128..511) is identically ZERO (antisymmetric CG vs v(x)v).
//  - e3nn l=1 basis order within an ori row: 0=y, 1=z, 2=x.
//  - cols 0..127:   w0[col] * |v|^2 / sqrt(3)
//  - cols 512..1151: j=col-512, w2[j/5] * s2[j%5],
//    s2 = [sqrt(2)xy, sqrt(2)yz, sqrt(1/6)(2z^2-x^2-y^2), sqrt(2)zx, sqrt(1/2)(x^2-y^2)]
// Pure write-stream: 460.8 MB fp32 out.
//
// FINAL (= v4, session best 93.6 us). Roofline model fitted across rounds 1-9:
//   time ~= 35 us (fixed dispatch/ramp, paid even by the native 1.8GB fill)
//         + bytes / 7.8 TB/s (steady-state stream, ~97% of HBM spec peak).
// Toggled with no effect: store continuity (v5), LDS dense regional bursts (v6,
// -19us), nontemporal stores (v7b), split fill-clone dispatch (v8, -4.6us).
// => 460.8 MB floor ~= 94 us; this kernel sits on it.
//
// Structure: each thread owns 28 consecutive rows x fixed column chunk-pair
// (chunks c and c+144 -> every wave store is a contiguous 1KB burst);
// 21x global_load_dwordx4 preload, one waitcnt, then 56 back-to-back stores.

#define THREADS 256
#define CPR 144                         // threads per row; row = 288 float4 chunks
#define GRID 2016                       // GRID*THREADS = 516096 = 3584 groups * 144
#define RPT 28                          // rows per thread (3584*28 = 100352 >= 100000)

__global__ __launch_bounds__(THREADS) void ori_embed_kernel(
    const float* __restrict__ ori,
    const float* __restrict__ weights,
    float* __restrict__ out,
    int n_rows)
{
    const int tid = blockIdx.x * THREADS + threadIdx.x;
    const int c = tid % CPR;            // chunk within row (owns chunks c and c+144)
    const int g = tid / CPR;            // row group
    const int r0 = g * RPT;

    // Columns owned: chunk A = cols 4c..4c+3, chunk B = cols 576+4c..576+4c+3.
    float coef[8];
    int sel[8];   // 0 -> s0 (l=0 value), 1..5 -> l=2 components
#pragma unroll
    for (int i = 0; i < 8; ++i) {
        const int col = (i < 4) ? (4 * c + i) : (576 + 4 * c + (i - 4));
        if (col < 128)      { coef[i] = weights[col];  sel[i] = 0; }
        else if (col < 512) { coef[i] = 0.0f;          sel[i] = 0; }
        else { const int j = col - 512;
               coef[i] = weights[256 + j / 5];         sel[i] = 1 + j % 5; }
    }

    float4* __restrict__ out4 = reinterpret_cast<float4*>(out);

    if (r0 + RPT <= n_rows) {
        // ---- fast path: preload all 28 rows (84 floats = 21 float4, 16B-aligned
        //      since 12*r0 = 336*g is a multiple of 16), then stream 56 stores ----
        union { float4 v[RPT * 3 / 4]; float f[RPT * 3]; } d;
        const float4* __restrict__ src =
            reinterpret_cast<const float4*>(ori + 3 * (size_t)r0);
#pragma unroll
        for (int k = 0; k < RPT * 3 / 4; ++k) d.v[k] = src[k];

#pragma unroll
        for (int j = 0; j < RPT; ++j) {
            const float vy = d.f[3 * j + 0];   // e3nn 0 = y
            const float vz = d.f[3 * j + 1];   // 1 = z
            const float vx = d.f[3 * j + 2];   // 2 = x
            const float xx = vx * vx, yy = vy * vy, zz = vz * vz;
            const float s0 = (xx + yy + zz) * 0.57735026918962576f;
            const float s1 = 1.41421356237309505f * (vx * vy);
            const float s2 = 1.41421356237309505f * (vy * vz);
            const float s3 = 0.40824829046386302f * (2.0f * zz - xx - yy);
            const float s4 = 1.41421356237309505f * (vz * vx);
            const float s5 = 0.70710678118654752f * (xx - yy);

            float r[8];
#pragma unroll
            for (int i = 0; i < 8; ++i) {
                float t = s0;
                t = (sel[i] == 1) ? s1 : t;
                t = (sel[i] == 2) ? s2 : t;
                t = (sel[i] == 3) ? s3 : t;
                t = (sel[i] == 4) ? s4 : t;
                t = (sel[i] == 5) ? s5 : t;
                r[i] = coef[i] * t;
            }
            const size_t base = (size_t)(r0 + j) * (2 * CPR) + c;
            out4[base]       = make_float4(r[0], r[1], r[2], r[3]);
            out4[base + CPR] = make_float4(r[4], r[5], r[6], r[7]);
        }
    } else {
        // ---- tail path (one partial group; a few idle groups past the end) ----
        for (int j = 0; r0 + j < n_rows; ++j) {
            const int n = r0 + j;
            const float vy = ori[3 * n + 0];
            const float vz = ori[3 * n + 1];
            const float vx = ori[3 * n + 2];
            const float xx = vx * vx, yy = vy * vy, zz = vz * vz;
            const float s0 = (xx + yy + zz) * 0.57735026918962576f;
            const float s1 = 1.41421356237309505f * (vx * vy);
            const float s2 = 1.41421356237309505f * (vy * vz);
            const float s3 = 0.40824829046386302f * (2.0f * zz - xx - yy);
            const float s4 = 1.41421356237309505f * (vz * vx);
            const float s5 = 0.70710678118654752f * (xx - yy);

            float r[8];
#pragma unroll
            for (int i = 0; i < 8; ++i) {
                float t = s0;
                t = (sel[i] == 1) ? s1 : t;
                t = (sel[i] == 2) ? s2 : t;
                t = (sel[i] == 3) ? s3 : t;
                t = (sel[i] == 4) ? s4 : t;
                t = (sel[i] == 5) ? s5 : t;
                r[i] = coef[i] * t;
            }
            const size_t base = (size_t)n * (2 * CPR) + c;
            out4[base]       = make_float4(r[0], r[1], r[2], r[3]);
            out4[base + CPR] = make_float4(r[4], r[5], r[6], r[7]);
        }
    }
}

extern "C" void kernel_launch(void* const* d_in, const int* in_sizes, int n_in,
                              void* d_out, int out_size, void* d_ws, size_t ws_size,
                              hipStream_t stream) {
    const float* ori = (const float*)d_in[0];
    const float* weights = (const float*)d_in[1];
    float* out = (float*)d_out;
    const int n_rows = in_sizes[0] / 3;

    hipLaunchKernelGGL(ori_embed_kernel, dim3(GRID), dim3(THREADS), 0, stream,
                       ori, weights, out, n_rows);
}